// Round 13
// baseline (258.086 us; speedup 1.0000x reference)
//
#include <hip/hip_runtime.h>
#include <math.h>

// Problem constants
#define B_ 2
#define L_ 1024
#define D_ 1024
#define D_INNER 2048
#define DT_RANK 64
#define N_STATE 16
#define NC 64          // scan chunks
#define LC 16          // L_/NC

typedef __attribute__((ext_vector_type(8))) short bf16x8;
typedef __attribute__((ext_vector_type(4))) float f32x4;

// ---- bf16 helpers (bit-level, RNE) ----
__device__ __forceinline__ unsigned short f2bf(float f) {
  unsigned int u = __float_as_uint(f);
  u += 0x7fffu + ((u >> 16) & 1u);
  return (unsigned short)(u >> 16);
}
__device__ __forceinline__ float bf2f(unsigned short s) {
  return __uint_as_float((unsigned int)s << 16);
}
__device__ __forceinline__ float softplus_f(float v) {
  return (v > 20.0f) ? v : log1pf(__expf(v));
}

// ---------------- prep: LN + weight converts + dblb zero + x->out copy ------
#define N4_WIN  1048576   // 4096*1024/4
#define N4_WOUT  524288   // 1024*2048/4
#define N4_WDT    32768   // 2048*64/4
#define N4_WXP    65536   // 128*2048/4 (padded out)
#define N4_ZERO   49152   // 2048*96/4 (dblb zero)
#define N4_CPY   524288   // 2048*1024/4 (x -> out residual pre-fill)
#define PREP_F4 (N4_WIN + N4_WOUT + N4_WDT + N4_WXP + N4_ZERO + N4_CPY)
#define PREP_BLOCKS (2048 + (PREP_F4 + 255) / 256)

__global__ __launch_bounds__(256) void prep_kernel(const float* __restrict__ x,
                                                   const float* __restrict__ w,
                                                   const float* __restrict__ b,
                                                   unsigned short* __restrict__ xn_b,
                                                   const float* __restrict__ W_in,
                                                   const float* __restrict__ W_out,
                                                   const float* __restrict__ W_dt,
                                                   const float* __restrict__ W_xp,
                                                   unsigned short* __restrict__ Win_b,
                                                   unsigned short* __restrict__ Wout_b,
                                                   unsigned short* __restrict__ Wdt_b,
                                                   unsigned short* __restrict__ Wxp_b,
                                                   float* __restrict__ dblb,
                                                   float* __restrict__ outb) {
  if (blockIdx.x < 2048) {
    int row = blockIdx.x;
    int tid = threadIdx.x;
    const float* xr = x + (size_t)row * D_;
    float4 v = ((const float4*)xr)[tid];
    float s  = v.x + v.y + v.z + v.w;
    float s2 = v.x*v.x + v.y*v.y + v.z*v.z + v.w*v.w;
    #pragma unroll
    for (int off = 32; off > 0; off >>= 1) {
      s  += __shfl_down(s, off);
      s2 += __shfl_down(s2, off);
    }
    __shared__ float ss[4], ss2[4];
    int wid = tid >> 6, lane = tid & 63;
    if (lane == 0) { ss[wid] = s; ss2[wid] = s2; }
    __syncthreads();
    if (tid == 0) {
      float a  = ss[0] + ss[1] + ss[2] + ss[3];
      float a2 = ss2[0] + ss2[1] + ss2[2] + ss2[3];
      ss[0]  = a  * (1.0f / D_);
      ss2[0] = a2 * (1.0f / D_);
    }
    __syncthreads();
    float mu = ss[0];
    float var = ss2[0] - mu * mu;
    float rstd = rsqrtf(var + 1e-5f);
    float4 wv = ((const float4*)w)[tid];
    float4 bv = ((const float4*)b)[tid];
    ushort4 o;
    o.x = f2bf((v.x - mu) * rstd * wv.x + bv.x);
    o.y = f2bf((v.y - mu) * rstd * wv.y + bv.y);
    o.z = f2bf((v.z - mu) * rstd * wv.z + bv.z);
    o.w = f2bf((v.w - mu) * rstd * wv.w + bv.w);
    ((ushort4*)(xn_b + (size_t)row * D_))[tid] = o;
    return;
  }
  int i = (blockIdx.x - 2048) * 256 + threadIdx.x;
  if (i < N4_WIN) {
    float4 v = ((const float4*)W_in)[i];
    ushort4 o; o.x = f2bf(v.x); o.y = f2bf(v.y); o.z = f2bf(v.z); o.w = f2bf(v.w);
    ((ushort4*)Win_b)[i] = o;
    return;
  }
  i -= N4_WIN;
  if (i < N4_WOUT) {
    float4 v = ((const float4*)W_out)[i];
    ushort4 o; o.x = f2bf(v.x); o.y = f2bf(v.y); o.z = f2bf(v.z); o.w = f2bf(v.w);
    ((ushort4*)Wout_b)[i] = o;
    return;
  }
  i -= N4_WOUT;
  if (i < N4_WDT) {
    float4 v = ((const float4*)W_dt)[i];
    ushort4 o; o.x = f2bf(v.x); o.y = f2bf(v.y); o.z = f2bf(v.z); o.w = f2bf(v.w);
    ((ushort4*)Wdt_b)[i] = o;
    return;
  }
  i -= N4_WDT;
  if (i < N4_WXP) {
    int row = (i * 4) >> 11;
    ushort4 o = make_ushort4(0, 0, 0, 0);
    if (row < 96) {
      float4 v = ((const float4*)W_xp)[i];
      o.x = f2bf(v.x); o.y = f2bf(v.y); o.z = f2bf(v.z); o.w = f2bf(v.w);
    }
    ((ushort4*)Wxp_b)[i] = o;
    return;
  }
  i -= N4_WXP;
  if (i < N4_ZERO) {
    ((float4*)dblb)[i] = make_float4(0.f, 0.f, 0.f, 0.f);
    return;
  }
  i -= N4_ZERO;
  if (i < N4_CPY) {
    ((float4*)outb)[i] = ((const float4*)x)[i];
  }
}

// ---------------- bf16 MFMA GEMM: C[M][N] = A[M][K] * B[N][K]^T ----------------
// BMT x 128 tile, 256 thr (4 waves 2x2), BK=64, global_load_lds(16B) staging,
// XOR swizzle (linear LDS dest + inverse-swizzled global source + swizzled read),
// XCD-aware block swizzle (requires nwg % 8 == 0 — all our grids qualify).
// EPI: 1 = bf16 C;
//      4 = split-K over grid.z, fp32 atomicAdd into Cf (dbl path, Cf pre-zeroed);
//      5 = bf16 C = softplus(v + ep0[c]); A reg-staged from fp32 Af32 (lda=96);
//      7 = split-K over grid.z, fp32 atomicAdd into Cf (out pre-filled with residual)
template<int EPI, int BMT>
__global__ __launch_bounds__(256) void gemm_mfma(const unsigned short* __restrict__ A, int lda,
                                                 const unsigned short* __restrict__ B, int ldb,
                                                 float* __restrict__ Cf,
                                                 unsigned short* __restrict__ Cb,
                                                 int ldc, int Nguard, int K,
                                                 const float* __restrict__ ep0,
                                                 const float* __restrict__ Af32 = nullptr) {
  __shared__ unsigned short As[BMT * 64];
  __shared__ unsigned short Bs[128 * 64];
  const int tid = threadIdx.x;
  const int lane = tid & 63;
  const int w = tid >> 6;
  const int wr = w >> 1, wc = w & 1;
  // XCD-aware swizzle on the (x,y) plane
  int flat = blockIdx.y * gridDim.x + blockIdx.x;
  int nwg = gridDim.x * gridDim.y;
  int q8 = nwg >> 3;
  int swz = (flat & 7) * q8 + (flat >> 3);
  const int bm = (swz / gridDim.x) * BMT;
  const int bn = (swz % gridDim.x) * 128;
  const int l16 = lane & 15;
  constexpr int MW = BMT / 32;           // M-frags per wave

  int kbeg = 0, kend = K;
  if (EPI == 4 || EPI == 7) {
    int ks = K / gridDim.z;
    kbeg = blockIdx.z * ks;
    kend = kbeg + ks;
  }

  f32x4 acc[MW][4];
  #pragma unroll
  for (int m = 0; m < MW; ++m)
    #pragma unroll
    for (int n = 0; n < 4; ++n) acc[m][n] = (f32x4){0.f, 0.f, 0.f, 0.f};

  for (int k0 = kbeg; k0 < kend; k0 += 64) {
    // stage A tile
    if constexpr (EPI == 5) {
      // reg-stage from fp32 source (cols 0..63 of stride-lda rows), inline cvt
      #pragma unroll
      for (int i = 0; i < BMT / 32; ++i) {
        int p = (i * 256 + tid) * 16;      // linear byte offset in tile
        int r = p >> 7;
        int s = (p >> 4) & 7;
        int cb = ((s ^ (r & 7)) << 3);
        const float* ga = Af32 + (size_t)(bm + r) * lda + cb;
        float4 v0 = *(const float4*)ga;
        float4 v1 = *(const float4*)(ga + 4);
        ushort4 u0 = make_ushort4(f2bf(v0.x), f2bf(v0.y), f2bf(v0.z), f2bf(v0.w));
        ushort4 u1 = make_ushort4(f2bf(v1.x), f2bf(v1.y), f2bf(v1.z), f2bf(v1.w));
        *(ushort4*)(As + (p >> 1)) = u0;
        *(ushort4*)(As + (p >> 1) + 4) = u1;
      }
    } else {
      #pragma unroll
      for (int i = 0; i < BMT / 32; ++i) {
        int p = (i * 256 + tid) * 16;      // linear byte offset in tile
        int r = p >> 7;                    // 128 B per row
        int s = (p >> 4) & 7;              // 16B slot in row
        int cb = ((s ^ (r & 7)) << 3);     // swizzled source element col
        const unsigned short* ga = A + (size_t)(bm + r) * lda + k0 + cb;
        __builtin_amdgcn_global_load_lds(
            (const __attribute__((address_space(1))) void*)ga,
            (__attribute__((address_space(3))) void*)(As + (p >> 1)), 16, 0, 0);
      }
    }
    #pragma unroll
    for (int i = 0; i < 4; ++i) {
      int p = (i * 256 + tid) * 16;
      int r = p >> 7;
      int s = (p >> 4) & 7;
      int cb = ((s ^ (r & 7)) << 3);
      const unsigned short* gb = B + (size_t)(bn + r) * ldb + k0 + cb;
      __builtin_amdgcn_global_load_lds(
          (const __attribute__((address_space(1))) void*)gb,
          (__attribute__((address_space(3))) void*)(Bs + (p >> 1)), 16, 0, 0);
    }
    __syncthreads();
    #pragma unroll
    for (int ks = 0; ks < 2; ++ks) {
      const int slot = ks * 4 + (lane >> 4);
      bf16x8 af[MW], bfr[4];
      #pragma unroll
      for (int m = 0; m < MW; ++m) {
        int ar = wr * (BMT / 2) + m * 16 + l16;
        af[m] = *(const bf16x8*)(As + ar * 64 + ((slot ^ (ar & 7)) << 3));
      }
      #pragma unroll
      for (int n = 0; n < 4; ++n) {
        int br = wc * 64 + n * 16 + l16;
        bfr[n] = *(const bf16x8*)(Bs + br * 64 + ((slot ^ (br & 7)) << 3));
      }
      #pragma unroll
      for (int m = 0; m < MW; ++m)
        #pragma unroll
        for (int n = 0; n < 4; ++n)
          acc[m][n] = __builtin_amdgcn_mfma_f32_16x16x32_bf16(af[m], bfr[n], acc[m][n], 0, 0, 0);
    }
    __syncthreads();
  }

  // epilogue: C row = (lane>>4)*4 + reg, col = lane&15 per fragment
  const int crow0 = bm + wr * (BMT / 2) + (lane >> 4) * 4;
  const int ccol0 = bn + wc * 64 + l16;
  #pragma unroll
  for (int m = 0; m < MW; ++m) {
    #pragma unroll
    for (int n = 0; n < 4; ++n) {
      int c = ccol0 + n * 16;
      if (c >= Nguard) continue;
      #pragma unroll
      for (int r = 0; r < 4; ++r) {
        int rr = crow0 + m * 16 + r;
        float v = acc[m][n][r];
        if (EPI == 1) {
          Cb[(size_t)rr * ldc + c] = f2bf(v);
        } else if (EPI == 4 || EPI == 7) {
          atomicAdd(&Cf[(size_t)rr * ldc + c], v);
        } else if (EPI == 5) {
          Cb[(size_t)rr * ldc + c] = f2bf(softplus_f(v + ep0[c]));
        } else {
          Cf[(size_t)rr * ldc + c] = v;
        }
      }
    }
  }
}

// ---------------- Conv1d (depthwise, K=4, causal) + SiLU, bf16 in/out --------
__global__ __launch_bounds__(256) void conv_silu_kernel(const unsigned short* __restrict__ xz,
                                                        const float* __restrict__ Wc,
                                                        const float* __restrict__ bc,
                                                        unsigned short* __restrict__ xcb) {
  int idx = blockIdx.x * 256 + threadIdx.x;   // (b*L+t)*D_INNER + e
  int e = idx & (D_INNER - 1);
  int t = (idx >> 11) & (L_ - 1);
  int bt = idx >> 11;                         // b*L + t
  float acc = bc[e];
  float w0 = Wc[e * 4 + 0], w1 = Wc[e * 4 + 1], w2 = Wc[e * 4 + 2], w3 = Wc[e * 4 + 3];
  const unsigned short* base = xz + (size_t)bt * 4096 + e;   // xs half of xz row
  if (t >= 3) acc = fmaf(bf2f(base[-3 * 4096]), w0, acc);
  if (t >= 2) acc = fmaf(bf2f(base[-2 * 4096]), w1, acc);
  if (t >= 1) acc = fmaf(bf2f(base[-1 * 4096]), w2, acc);
  acc = fmaf(bf2f(base[0]), w3, acc);
  float s = acc / (1.0f + __expf(-acc));
  xcb[idx] = f2bf(s);
}

// ---------------- Scan phase 1: per-chunk (prod dA, local state) ----------------
__global__ __launch_bounds__(256) void scan1_kernel(const unsigned short* __restrict__ delta,
                                                    const unsigned short* __restrict__ xc,
                                                    const float* __restrict__ dbl,
                                                    const float* __restrict__ A_log,
                                                    float* __restrict__ P,
                                                    float* __restrict__ Q) {
  int e = blockIdx.x * 256 + threadIdx.x;
  int b = blockIdx.y, c = blockIdx.z;
  const int t0 = (int)(b * L_ + c * LC);

  __shared__ float sB[LC][N_STATE];     // 1 KB
  {
    int step = threadIdx.x >> 4, n = threadIdx.x & 15;
    sB[step][n] = dbl[(size_t)(t0 + step) * 96 + 64 + n];
  }
  __syncthreads();

  float An[N_STATE];
  #pragma unroll
  for (int q = 0; q < 4; ++q) {
    float4 v = *(const float4*)&A_log[(size_t)e * N_STATE + q * 4];
    An[q*4+0] = -__expf(v.x); An[q*4+1] = -__expf(v.y);
    An[q*4+2] = -__expf(v.z); An[q*4+3] = -__expf(v.w);
  }
  float h[N_STATE], p[N_STATE];
  #pragma unroll
  for (int n = 0; n < N_STATE; ++n) { h[n] = 0.f; p[n] = 1.f; }

  const size_t row0 = (size_t)t0 * D_INNER + e;
  float dlt = bf2f(delta[row0]);
  float xcv = bf2f(xc[row0]);

  for (int tt = 0; tt < LC; ++tt) {
    float ndlt = 0.f, nxcv = 0.f;
    if (tt + 1 < LC) {
      ndlt = bf2f(delta[row0 + (size_t)(tt + 1) * D_INNER]);
      nxcv = bf2f(xc[row0 + (size_t)(tt + 1) * D_INNER]);
    }
    float dbx = dlt * xcv;
    #pragma unroll
    for (int n = 0; n < N_STATE; ++n) {
      float da = __expf(dlt * An[n]);
      h[n] = fmaf(da, h[n], dbx * sB[tt][n]);
      p[n] *= da;
    }
    dlt = ndlt; xcv = nxcv;
  }
  size_t o = ((size_t)(c * B_ + b) * N_STATE) * D_INNER + e;
  #pragma unroll
  for (int n = 0; n < N_STATE; ++n) {
    P[o + (size_t)n * D_INNER] = p[n];
    Q[o + (size_t)n * D_INNER] = h[n];
  }
}

// ---------------- Scan phase 2: combine chunk states (Hinit in-place in Q) ----
__global__ __launch_bounds__(256) void scan2_kernel(const float* __restrict__ P,
                                                    float* __restrict__ Q) {
  int idx = blockIdx.x * 256 + threadIdx.x;  // B_*N_STATE*D_INNER = 65536
  float H = 0.f;
  #pragma unroll
  for (int c = 0; c < NC; ++c) {
    size_t o = (size_t)c * (B_ * N_STATE * D_INNER) + idx;
    float p = P[o], q = Q[o];
    Q[o] = H;                         // Hinit for chunk c
    H = fmaf(p, H, q);
  }
}

// ---------------- Scan phase 3: replay + fused gate -> y (bf16) ----------------
__global__ __launch_bounds__(256) void scan3_kernel(const unsigned short* __restrict__ delta,
                                                    const unsigned short* __restrict__ xc,
                                                    const float* __restrict__ dbl,
                                                    const float* __restrict__ A_log,
                                                    const float* __restrict__ Hinit,
                                                    const unsigned short* __restrict__ xz,
                                                    const float* __restrict__ Dsk,
                                                    unsigned short* __restrict__ y) {
  int e = blockIdx.x * 256 + threadIdx.x;
  int b = blockIdx.y, c = blockIdx.z;
  const int t0 = (int)(b * L_ + c * LC);

  __shared__ float sB[LC][N_STATE];     // 1 KB
  __shared__ float sC[LC][N_STATE];     // 1 KB
  {
    int step = threadIdx.x >> 4, n = threadIdx.x & 15;
    const float* row = dbl + (size_t)(t0 + step) * 96;
    sB[step][n] = row[64 + n];
    sC[step][n] = row[80 + n];
  }
  __syncthreads();

  float An[N_STATE];
  #pragma unroll
  for (int q = 0; q < 4; ++q) {
    float4 v = *(const float4*)&A_log[(size_t)e * N_STATE + q * 4];
    An[q*4+0] = -__expf(v.x); An[q*4+1] = -__expf(v.y);
    An[q*4+2] = -__expf(v.z); An[q*4+3] = -__expf(v.w);
  }
  float h[N_STATE];
  {
    size_t o = ((size_t)(c * B_ + b) * N_STATE) * D_INNER + e;
    #pragma unroll
    for (int n = 0; n < N_STATE; ++n) h[n] = Hinit[o + (size_t)n * D_INNER];
  }
  float dskip = Dsk[e];
  const size_t row0 = (size_t)t0 * D_INNER + e;
  const size_t zrow0 = (size_t)t0 * 4096 + D_INNER + e;

  float dlt = bf2f(delta[row0]);
  float xcv = bf2f(xc[row0]);
  float zv  = bf2f(xz[zrow0]);

  for (int tt = 0; tt < LC; ++tt) {
    float ndlt = 0.f, nxcv = 0.f, nzv = 0.f;
    if (tt + 1 < LC) {
      ndlt = bf2f(delta[row0 + (size_t)(tt + 1) * D_INNER]);
      nxcv = bf2f(xc[row0 + (size_t)(tt + 1) * D_INNER]);
      nzv  = bf2f(xz[zrow0 + (size_t)(tt + 1) * 4096]);
    }
    float dbx = dlt * xcv;
    float yv = 0.f;
    #pragma unroll
    for (int n = 0; n < N_STATE; ++n) {
      float da = __expf(dlt * An[n]);
      h[n] = fmaf(da, h[n], dbx * sB[tt][n]);
      yv = fmaf(h[n], sC[tt][n], yv);
    }
    float gate = zv / (1.0f + __expf(-zv));
    y[row0 + (size_t)tt * D_INNER] = f2bf((yv + dskip * xcv) * gate);
    dlt = ndlt; xcv = nxcv; zv = nzv;
  }
}

// ---------------- launch ----------------
extern "C" void kernel_launch(void* const* d_in, const int* in_sizes, int n_in,
                              void* d_out, int out_size, void* d_ws, size_t ws_size,
                              hipStream_t stream) {
  const float* x       = (const float*)d_in[0];
  const float* ln_w    = (const float*)d_in[1];
  const float* ln_b    = (const float*)d_in[2];
  const float* W_in    = (const float*)d_in[3];
  const float* W_conv  = (const float*)d_in[4];
  const float* b_conv  = (const float*)d_in[5];
  const float* W_xproj = (const float*)d_in[6];
  const float* W_dt    = (const float*)d_in[7];
  const float* b_dt    = (const float*)d_in[8];
  const float* A_log   = (const float*)d_in[9];
  const float* D_skip  = (const float*)d_in[10];
  const float* W_out   = (const float*)d_in[11];
  float* out = (float*)d_out;

  const size_t BL = (size_t)B_ * L_;            // 2048
  // fp32 region (plain linear layout, no aliasing)
  float* dblb = (float*)d_ws;                   // 196,608 f (atomic accumulator)
  float* P    = dblb + 196608;                  // 4,194,304 f (NC=64)
  float* Q    = P    + 4194304;                 // 4,194,304 f
  // bf16 region
  unsigned short* xn_b    = (unsigned short*)(Q + 4194304);
  unsigned short* Win_b   = xn_b    + 2097152;  // 4096*1024
  unsigned short* xz_b    = Win_b   + 4194304;  // 2048*4096
  unsigned short* xc_b    = xz_b    + 8388608;  // 2048*2048
  unsigned short* Wxp_b   = xc_b    + 4194304;  // 128*2048 (padded)
  unsigned short* y_b     = Wxp_b   + 262144;   // 2048*2048
  unsigned short* Wout_b  = y_b     + 4194304;  // 1024*2048
  unsigned short* Wdt_b   = Wout_b  + 2097152;  // 2048*64
  unsigned short* delta_b = Wdt_b   + 131072;   // 2048*2048

  // 1. prep: LN + weight converts + dblb zero + x->out copy (one launch)
  prep_kernel<<<PREP_BLOCKS, 256, 0, stream>>>(
      x, ln_w, ln_b, xn_b, W_in, W_out, W_dt, W_xproj,
      Win_b, Wout_b, Wdt_b, Wxp_b, dblb, out);
  // 2. input GEMM: xz = xn @ W_in^T  (M=2048, N=4096, K=1024), bf16 out
  gemm_mfma<1, 128><<<dim3(32, 16), 256, 0, stream>>>(
      xn_b, D_, Win_b, D_, nullptr, xz_b, 4096, 4096, D_, nullptr);
  // 3. conv + silu -> xc_b (bf16)
  conv_silu_kernel<<<(BL * D_INNER) / 256, 256, 0, stream>>>(xz_b, W_conv, b_conv, xc_b);
  // 4. dbl = xc @ W_xproj^T  split-K x16, fp32 atomicAdd into pre-zeroed dblb
  gemm_mfma<4, 128><<<dim3(1, 16, 16), 256, 0, stream>>>(
      xc_b, D_INNER, Wxp_b, D_INNER, dblb, nullptr, 96, 96, D_INNER, nullptr);
  // 5. delta = softplus(dt_low @ W_dt^T + b_dt) -> bf16; A reg-staged from fp32 dblb
  gemm_mfma<5, 128><<<dim3(16, 16), 256, 0, stream>>>(
      nullptr, 96, Wdt_b, DT_RANK, nullptr, delta_b, D_INNER, D_INNER, DT_RANK, b_dt, dblb);
  // 6. chunked scan (NC=64, 3 kernels — proven correct)
  scan1_kernel<<<dim3(D_INNER / 256, B_, NC), 256, 0, stream>>>(delta_b, xc_b, dblb, A_log, P, Q);
  scan2_kernel<<<(B_ * N_STATE * D_INNER) / 256, 256, 0, stream>>>(P, Q);
  scan3_kernel<<<dim3(D_INNER / 256, B_, NC), 256, 0, stream>>>(delta_b, xc_b, dblb, A_log, Q,
                                                                xz_b, D_skip, y_b);
  // 7. out += y @ W_out^T  (split-K x2, atomicAdd; out pre-filled with residual x)
  gemm_mfma<7, 64><<<dim3(8, 32, 2), 256, 0, stream>>>(
      y_b, D_INNER, Wout_b, D_INNER, out, nullptr, D_, D_, D_INNER, nullptr);
}

// Round 14
// 250.507 us; speedup vs baseline: 1.0303x; 1.0303x over previous
//
#include <hip/hip_runtime.h>
#include <math.h>

// Problem constants
#define B_ 2
#define L_ 1024
#define D_ 1024
#define D_INNER 2048
#define DT_RANK 64
#define N_STATE 16
#define NC 64          // scan chunks
#define LC 16          // L_/NC

typedef __attribute__((ext_vector_type(8))) short bf16x8;
typedef __attribute__((ext_vector_type(4))) float f32x4;

// ---- bf16 helpers (bit-level, RNE) ----
__device__ __forceinline__ unsigned short f2bf(float f) {
  unsigned int u = __float_as_uint(f);
  u += 0x7fffu + ((u >> 16) & 1u);
  return (unsigned short)(u >> 16);
}
__device__ __forceinline__ float bf2f(unsigned short s) {
  return __uint_as_float((unsigned int)s << 16);
}
__device__ __forceinline__ float softplus_f(float v) {
  return (v > 20.0f) ? v : log1pf(__expf(v));
}

// ---------------- prep: LN + weight converts + dblb zero + x->out copy ------
#define N4_WIN  1048576   // 4096*1024/4
#define N4_WOUT  524288   // 1024*2048/4
#define N4_WDT    32768   // 2048*64/4
#define N4_WXP    65536   // 128*2048/4 (padded out)
#define N4_ZERO   49152   // 2048*96/4 (dblb zero)
#define N4_CPY   524288   // 2048*1024/4 (x -> out residual pre-fill)
#define PREP_F4 (N4_WIN + N4_WOUT + N4_WDT + N4_WXP + N4_ZERO + N4_CPY)
#define PREP_BLOCKS (2048 + (PREP_F4 + 255) / 256)

__global__ __launch_bounds__(256) void prep_kernel(const float* __restrict__ x,
                                                   const float* __restrict__ w,
                                                   const float* __restrict__ b,
                                                   unsigned short* __restrict__ xn_b,
                                                   const float* __restrict__ W_in,
                                                   const float* __restrict__ W_out,
                                                   const float* __restrict__ W_dt,
                                                   const float* __restrict__ W_xp,
                                                   unsigned short* __restrict__ Win_b,
                                                   unsigned short* __restrict__ Wout_b,
                                                   unsigned short* __restrict__ Wdt_b,
                                                   unsigned short* __restrict__ Wxp_b,
                                                   float* __restrict__ dblb,
                                                   float* __restrict__ outb) {
  if (blockIdx.x < 2048) {
    int row = blockIdx.x;
    int tid = threadIdx.x;
    const float* xr = x + (size_t)row * D_;
    float4 v = ((const float4*)xr)[tid];
    float s  = v.x + v.y + v.z + v.w;
    float s2 = v.x*v.x + v.y*v.y + v.z*v.z + v.w*v.w;
    #pragma unroll
    for (int off = 32; off > 0; off >>= 1) {
      s  += __shfl_down(s, off);
      s2 += __shfl_down(s2, off);
    }
    __shared__ float ss[4], ss2[4];
    int wid = tid >> 6, lane = tid & 63;
    if (lane == 0) { ss[wid] = s; ss2[wid] = s2; }
    __syncthreads();
    if (tid == 0) {
      float a  = ss[0] + ss[1] + ss[2] + ss[3];
      float a2 = ss2[0] + ss2[1] + ss2[2] + ss2[3];
      ss[0]  = a  * (1.0f / D_);
      ss2[0] = a2 * (1.0f / D_);
    }
    __syncthreads();
    float mu = ss[0];
    float var = ss2[0] - mu * mu;
    float rstd = rsqrtf(var + 1e-5f);
    float4 wv = ((const float4*)w)[tid];
    float4 bv = ((const float4*)b)[tid];
    ushort4 o;
    o.x = f2bf((v.x - mu) * rstd * wv.x + bv.x);
    o.y = f2bf((v.y - mu) * rstd * wv.y + bv.y);
    o.z = f2bf((v.z - mu) * rstd * wv.z + bv.z);
    o.w = f2bf((v.w - mu) * rstd * wv.w + bv.w);
    ((ushort4*)(xn_b + (size_t)row * D_))[tid] = o;
    return;
  }
  int i = (blockIdx.x - 2048) * 256 + threadIdx.x;
  if (i < N4_WIN) {
    float4 v = ((const float4*)W_in)[i];
    ushort4 o; o.x = f2bf(v.x); o.y = f2bf(v.y); o.z = f2bf(v.z); o.w = f2bf(v.w);
    ((ushort4*)Win_b)[i] = o;
    return;
  }
  i -= N4_WIN;
  if (i < N4_WOUT) {
    float4 v = ((const float4*)W_out)[i];
    ushort4 o; o.x = f2bf(v.x); o.y = f2bf(v.y); o.z = f2bf(v.z); o.w = f2bf(v.w);
    ((ushort4*)Wout_b)[i] = o;
    return;
  }
  i -= N4_WOUT;
  if (i < N4_WDT) {
    float4 v = ((const float4*)W_dt)[i];
    ushort4 o; o.x = f2bf(v.x); o.y = f2bf(v.y); o.z = f2bf(v.z); o.w = f2bf(v.w);
    ((ushort4*)Wdt_b)[i] = o;
    return;
  }
  i -= N4_WDT;
  if (i < N4_WXP) {
    int row = (i * 4) >> 11;
    ushort4 o = make_ushort4(0, 0, 0, 0);
    if (row < 96) {
      float4 v = ((const float4*)W_xp)[i];
      o.x = f2bf(v.x); o.y = f2bf(v.y); o.z = f2bf(v.z); o.w = f2bf(v.w);
    }
    ((ushort4*)Wxp_b)[i] = o;
    return;
  }
  i -= N4_WXP;
  if (i < N4_ZERO) {
    ((float4*)dblb)[i] = make_float4(0.f, 0.f, 0.f, 0.f);
    return;
  }
  i -= N4_ZERO;
  if (i < N4_CPY) {
    ((float4*)outb)[i] = ((const float4*)x)[i];
  }
}

// ---------------- bf16 MFMA GEMM: C[M][N] = A[M][K] * B[N][K]^T ----------------
// BMT x 128 tile, 256 thr (4 waves 2x2), BK=64, global_load_lds(16B) staging,
// XOR swizzle (linear LDS dest + inverse-swizzled global source + swizzled read),
// XCD-aware block swizzle (requires nwg % 8 == 0 — all our grids qualify).
// EPI: 1 = bf16 C;
//      5 = bf16 C = softplus(v + ep0[c]); A reg-staged from fp32 Af32 (lda=96);
//      6 = dbl path: split-K over grid.z, fp32 atomicAdd into Cf (pre-zeroed);
//          A computed on the fly = conv_silu(xz) [A=xz bf16, lda=4096,
//          ep0=b_conv, Af32=W_conv], xc written to Cb as side effect;
//      7 = split-K over grid.z, fp32 atomicAdd into Cf (out pre-filled w/ residual)
template<int EPI, int BMT>
__global__ __launch_bounds__(256) void gemm_mfma(const unsigned short* __restrict__ A, int lda,
                                                 const unsigned short* __restrict__ B, int ldb,
                                                 float* __restrict__ Cf,
                                                 unsigned short* __restrict__ Cb,
                                                 int ldc, int Nguard, int K,
                                                 const float* __restrict__ ep0,
                                                 const float* __restrict__ Af32 = nullptr) {
  __shared__ unsigned short As[BMT * 64];
  __shared__ unsigned short Bs[128 * 64];
  const int tid = threadIdx.x;
  const int lane = tid & 63;
  const int w = tid >> 6;
  const int wr = w >> 1, wc = w & 1;
  // XCD-aware swizzle on the (x,y) plane
  int flat = blockIdx.y * gridDim.x + blockIdx.x;
  int nwg = gridDim.x * gridDim.y;
  int q8 = nwg >> 3;
  int swz = (flat & 7) * q8 + (flat >> 3);
  const int bm = (swz / gridDim.x) * BMT;
  const int bn = (swz % gridDim.x) * 128;
  const int l16 = lane & 15;
  constexpr int MW = BMT / 32;           // M-frags per wave

  int kbeg = 0, kend = K;
  if (EPI == 6 || EPI == 7) {
    int ks = K / gridDim.z;
    kbeg = blockIdx.z * ks;
    kend = kbeg + ks;
  }

  f32x4 acc[MW][4];
  #pragma unroll
  for (int m = 0; m < MW; ++m)
    #pragma unroll
    for (int n = 0; n < 4; ++n) acc[m][n] = (f32x4){0.f, 0.f, 0.f, 0.f};

  for (int k0 = kbeg; k0 < kend; k0 += 64) {
    // ---- stage A tile ----
    if constexpr (EPI == 5) {
      // reg-stage from fp32 source (cols 0..63 of stride-lda rows), inline cvt
      #pragma unroll
      for (int i = 0; i < BMT / 32; ++i) {
        int p = (i * 256 + tid) * 16;
        int r = p >> 7;
        int s = (p >> 4) & 7;
        int cb = ((s ^ (r & 7)) << 3);
        const float* ga = Af32 + (size_t)(bm + r) * lda + cb;
        float4 v0 = *(const float4*)ga;
        float4 v1 = *(const float4*)(ga + 4);
        ushort4 u0 = make_ushort4(f2bf(v0.x), f2bf(v0.y), f2bf(v0.z), f2bf(v0.w));
        ushort4 u1 = make_ushort4(f2bf(v1.x), f2bf(v1.y), f2bf(v1.z), f2bf(v1.w));
        *(ushort4*)(As + (p >> 1)) = u0;
        *(ushort4*)(As + (p >> 1) + 4) = u1;
      }
    } else if constexpr (EPI == 6) {
      // conv+silu on the fly: A = xz (bf16, row stride lda=4096), taps from
      // rows t-3..t; also write the computed xc tile to Cb (each (t,e) covered
      // exactly once across the (my,z) grid).
      #pragma unroll
      for (int i = 0; i < BMT / 32; ++i) {
        int p = (i * 256 + tid) * 16;
        int r = p >> 7;                    // t-row within tile
        int s = (p >> 4) & 7;
        int cb = ((s ^ (r & 7)) << 3);     // swizzled e-col (0..63) in this K-step
        int tg = bm + r;                   // global b*L + t
        int tt = tg & (L_ - 1);            // t within sequence
        int e  = k0 + cb;                  // global e (k0 includes z offset)
        const unsigned short* bp = A + (size_t)tg * lda + e;
        bf16x8 x0 = *(const bf16x8*)bp;
        bf16x8 xm1 = (bf16x8)(short)0, xm2 = (bf16x8)(short)0, xm3 = (bf16x8)(short)0;
        if (tt >= 1) xm1 = *(const bf16x8*)(bp - lda);
        if (tt >= 2) xm2 = *(const bf16x8*)(bp - 2 * lda);
        if (tt >= 3) xm3 = *(const bf16x8*)(bp - 3 * lda);
        unsigned short res[8];
        #pragma unroll
        for (int j = 0; j < 8; ++j) {
          float4 wv = ((const float4*)Af32)[e + j];   // W_conv[e+j][0..3]
          float a = ep0[e + j];                       // b_conv
          a = fmaf(bf2f((unsigned short)xm3[j]), wv.x, a);
          a = fmaf(bf2f((unsigned short)xm2[j]), wv.y, a);
          a = fmaf(bf2f((unsigned short)xm1[j]), wv.z, a);
          a = fmaf(bf2f((unsigned short)x0[j]),  wv.w, a);
          float sv = a / (1.0f + __expf(-a));
          res[j] = f2bf(sv);
        }
        ushort4 u0 = make_ushort4(res[0], res[1], res[2], res[3]);
        ushort4 u1 = make_ushort4(res[4], res[5], res[6], res[7]);
        *(ushort4*)(As + (p >> 1)) = u0;
        *(ushort4*)(As + (p >> 1) + 4) = u1;
        unsigned short* xo = Cb + (size_t)tg * D_INNER + e;
        *(ushort4*)xo = u0;
        *(ushort4*)(xo + 4) = u1;
      }
    } else {
      #pragma unroll
      for (int i = 0; i < BMT / 32; ++i) {
        int p = (i * 256 + tid) * 16;      // linear byte offset in tile
        int r = p >> 7;                    // 128 B per row
        int s = (p >> 4) & 7;              // 16B slot in row
        int cb = ((s ^ (r & 7)) << 3);     // swizzled source element col
        const unsigned short* ga = A + (size_t)(bm + r) * lda + k0 + cb;
        __builtin_amdgcn_global_load_lds(
            (const __attribute__((address_space(1))) void*)ga,
            (__attribute__((address_space(3))) void*)(As + (p >> 1)), 16, 0, 0);
      }
    }
    // ---- stage B tile ----
    #pragma unroll
    for (int i = 0; i < 4; ++i) {
      int p = (i * 256 + tid) * 16;
      int r = p >> 7;
      int s = (p >> 4) & 7;
      int cb = ((s ^ (r & 7)) << 3);
      const unsigned short* gb = B + (size_t)(bn + r) * ldb + k0 + cb;
      __builtin_amdgcn_global_load_lds(
          (const __attribute__((address_space(1))) void*)gb,
          (__attribute__((address_space(3))) void*)(Bs + (p >> 1)), 16, 0, 0);
    }
    __syncthreads();
    #pragma unroll
    for (int ks = 0; ks < 2; ++ks) {
      const int slot = ks * 4 + (lane >> 4);
      bf16x8 af[MW], bfr[4];
      #pragma unroll
      for (int m = 0; m < MW; ++m) {
        int ar = wr * (BMT / 2) + m * 16 + l16;
        af[m] = *(const bf16x8*)(As + ar * 64 + ((slot ^ (ar & 7)) << 3));
      }
      #pragma unroll
      for (int n = 0; n < 4; ++n) {
        int br = wc * 64 + n * 16 + l16;
        bfr[n] = *(const bf16x8*)(Bs + br * 64 + ((slot ^ (br & 7)) << 3));
      }
      #pragma unroll
      for (int m = 0; m < MW; ++m)
        #pragma unroll
        for (int n = 0; n < 4; ++n)
          acc[m][n] = __builtin_amdgcn_mfma_f32_16x16x32_bf16(af[m], bfr[n], acc[m][n], 0, 0, 0);
    }
    __syncthreads();
  }

  // epilogue: C row = (lane>>4)*4 + reg, col = lane&15 per fragment
  const int crow0 = bm + wr * (BMT / 2) + (lane >> 4) * 4;
  const int ccol0 = bn + wc * 64 + l16;
  #pragma unroll
  for (int m = 0; m < MW; ++m) {
    #pragma unroll
    for (int n = 0; n < 4; ++n) {
      int c = ccol0 + n * 16;
      if (c >= Nguard) continue;
      #pragma unroll
      for (int r = 0; r < 4; ++r) {
        int rr = crow0 + m * 16 + r;
        float v = acc[m][n][r];
        if (EPI == 1) {
          Cb[(size_t)rr * ldc + c] = f2bf(v);
        } else if (EPI == 6 || EPI == 7) {
          atomicAdd(&Cf[(size_t)rr * ldc + c], v);
        } else if (EPI == 5) {
          Cb[(size_t)rr * ldc + c] = f2bf(softplus_f(v + ep0[c]));
        } else {
          Cf[(size_t)rr * ldc + c] = v;
        }
      }
    }
  }
}

// ---------------- Scan phase 1: per-chunk (prod dA, local state) ----------------
__global__ __launch_bounds__(256) void scan1_kernel(const unsigned short* __restrict__ delta,
                                                    const unsigned short* __restrict__ xc,
                                                    const float* __restrict__ dbl,
                                                    const float* __restrict__ A_log,
                                                    float* __restrict__ P,
                                                    float* __restrict__ Q) {
  int e = blockIdx.x * 256 + threadIdx.x;
  int b = blockIdx.y, c = blockIdx.z;
  const int t0 = (int)(b * L_ + c * LC);

  __shared__ float sB[LC][N_STATE];     // 1 KB
  {
    int step = threadIdx.x >> 4, n = threadIdx.x & 15;
    sB[step][n] = dbl[(size_t)(t0 + step) * 96 + 64 + n];
  }
  __syncthreads();

  float An[N_STATE];
  #pragma unroll
  for (int q = 0; q < 4; ++q) {
    float4 v = *(const float4*)&A_log[(size_t)e * N_STATE + q * 4];
    An[q*4+0] = -__expf(v.x); An[q*4+1] = -__expf(v.y);
    An[q*4+2] = -__expf(v.z); An[q*4+3] = -__expf(v.w);
  }
  float h[N_STATE], p[N_STATE];
  #pragma unroll
  for (int n = 0; n < N_STATE; ++n) { h[n] = 0.f; p[n] = 1.f; }

  const size_t row0 = (size_t)t0 * D_INNER + e;
  float dlt = bf2f(delta[row0]);
  float xcv = bf2f(xc[row0]);

  for (int tt = 0; tt < LC; ++tt) {
    float ndlt = 0.f, nxcv = 0.f;
    if (tt + 1 < LC) {
      ndlt = bf2f(delta[row0 + (size_t)(tt + 1) * D_INNER]);
      nxcv = bf2f(xc[row0 + (size_t)(tt + 1) * D_INNER]);
    }
    float dbx = dlt * xcv;
    #pragma unroll
    for (int n = 0; n < N_STATE; ++n) {
      float da = __expf(dlt * An[n]);
      h[n] = fmaf(da, h[n], dbx * sB[tt][n]);
      p[n] *= da;
    }
    dlt = ndlt; xcv = nxcv;
  }
  size_t o = ((size_t)(c * B_ + b) * N_STATE) * D_INNER + e;
  #pragma unroll
  for (int n = 0; n < N_STATE; ++n) {
    P[o + (size_t)n * D_INNER] = p[n];
    Q[o + (size_t)n * D_INNER] = h[n];
  }
}

// ---------------- Scan phase 2: combine chunk states (Hinit in-place in Q) ----
__global__ __launch_bounds__(256) void scan2_kernel(const float* __restrict__ P,
                                                    float* __restrict__ Q) {
  int idx = blockIdx.x * 256 + threadIdx.x;  // B_*N_STATE*D_INNER = 65536
  float H = 0.f;
  #pragma unroll
  for (int c = 0; c < NC; ++c) {
    size_t o = (size_t)c * (B_ * N_STATE * D_INNER) + idx;
    float p = P[o], q = Q[o];
    Q[o] = H;                         // Hinit for chunk c
    H = fmaf(p, H, q);
  }
}

// ---------------- Scan phase 3: replay + fused gate -> y (bf16) ----------------
__global__ __launch_bounds__(256) void scan3_kernel(const unsigned short* __restrict__ delta,
                                                    const unsigned short* __restrict__ xc,
                                                    const float* __restrict__ dbl,
                                                    const float* __restrict__ A_log,
                                                    const float* __restrict__ Hinit,
                                                    const unsigned short* __restrict__ xz,
                                                    const float* __restrict__ Dsk,
                                                    unsigned short* __restrict__ y) {
  int e = blockIdx.x * 256 + threadIdx.x;
  int b = blockIdx.y, c = blockIdx.z;
  const int t0 = (int)(b * L_ + c * LC);

  __shared__ float sB[LC][N_STATE];     // 1 KB
  __shared__ float sC[LC][N_STATE];     // 1 KB
  {
    int step = threadIdx.x >> 4, n = threadIdx.x & 15;
    const float* row = dbl + (size_t)(t0 + step) * 96;
    sB[step][n] = row[64 + n];
    sC[step][n] = row[80 + n];
  }
  __syncthreads();

  float An[N_STATE];
  #pragma unroll
  for (int q = 0; q < 4; ++q) {
    float4 v = *(const float4*)&A_log[(size_t)e * N_STATE + q * 4];
    An[q*4+0] = -__expf(v.x); An[q*4+1] = -__expf(v.y);
    An[q*4+2] = -__expf(v.z); An[q*4+3] = -__expf(v.w);
  }
  float h[N_STATE];
  {
    size_t o = ((size_t)(c * B_ + b) * N_STATE) * D_INNER + e;
    #pragma unroll
    for (int n = 0; n < N_STATE; ++n) h[n] = Hinit[o + (size_t)n * D_INNER];
  }
  float dskip = Dsk[e];
  const size_t row0 = (size_t)t0 * D_INNER + e;
  const size_t zrow0 = (size_t)t0 * 4096 + D_INNER + e;

  float dlt = bf2f(delta[row0]);
  float xcv = bf2f(xc[row0]);
  float zv  = bf2f(xz[zrow0]);

  for (int tt = 0; tt < LC; ++tt) {
    float ndlt = 0.f, nxcv = 0.f, nzv = 0.f;
    if (tt + 1 < LC) {
      ndlt = bf2f(delta[row0 + (size_t)(tt + 1) * D_INNER]);
      nxcv = bf2f(xc[row0 + (size_t)(tt + 1) * D_INNER]);
      nzv  = bf2f(xz[zrow0 + (size_t)(tt + 1) * 4096]);
    }
    float dbx = dlt * xcv;
    float yv = 0.f;
    #pragma unroll
    for (int n = 0; n < N_STATE; ++n) {
      float da = __expf(dlt * An[n]);
      h[n] = fmaf(da, h[n], dbx * sB[tt][n]);
      yv = fmaf(h[n], sC[tt][n], yv);
    }
    float gate = zv / (1.0f + __expf(-zv));
    y[row0 + (size_t)tt * D_INNER] = f2bf((yv + dskip * xcv) * gate);
    dlt = ndlt; xcv = nxcv; zv = nzv;
  }
}

// ---------------- launch ----------------
extern "C" void kernel_launch(void* const* d_in, const int* in_sizes, int n_in,
                              void* d_out, int out_size, void* d_ws, size_t ws_size,
                              hipStream_t stream) {
  const float* x       = (const float*)d_in[0];
  const float* ln_w    = (const float*)d_in[1];
  const float* ln_b    = (const float*)d_in[2];
  const float* W_in    = (const float*)d_in[3];
  const float* W_conv  = (const float*)d_in[4];
  const float* b_conv  = (const float*)d_in[5];
  const float* W_xproj = (const float*)d_in[6];
  const float* W_dt    = (const float*)d_in[7];
  const float* b_dt    = (const float*)d_in[8];
  const float* A_log   = (const float*)d_in[9];
  const float* D_skip  = (const float*)d_in[10];
  const float* W_out   = (const float*)d_in[11];
  float* out = (float*)d_out;

  const size_t BL = (size_t)B_ * L_;            // 2048
  // fp32 region (plain linear layout, no aliasing)
  float* dblb = (float*)d_ws;                   // 196,608 f (atomic accumulator)
  float* P    = dblb + 196608;                  // 4,194,304 f (NC=64)
  float* Q    = P    + 4194304;                 // 4,194,304 f
  // bf16 region
  unsigned short* xn_b    = (unsigned short*)(Q + 4194304);
  unsigned short* Win_b   = xn_b    + 2097152;  // 4096*1024
  unsigned short* xz_b    = Win_b   + 4194304;  // 2048*4096
  unsigned short* xc_b    = xz_b    + 8388608;  // 2048*2048
  unsigned short* Wxp_b   = xc_b    + 4194304;  // 128*2048 (padded)
  unsigned short* y_b     = Wxp_b   + 262144;   // 2048*2048
  unsigned short* Wout_b  = y_b     + 4194304;  // 1024*2048
  unsigned short* Wdt_b   = Wout_b  + 2097152;  // 2048*64
  unsigned short* delta_b = Wdt_b   + 131072;   // 2048*2048

  // 1. prep: LN + weight converts + dblb zero + x->out copy (one launch)
  prep_kernel<<<PREP_BLOCKS, 256, 0, stream>>>(
      x, ln_w, ln_b, xn_b, W_in, W_out, W_dt, W_xproj,
      Win_b, Wout_b, Wdt_b, Wxp_b, dblb, out);
  // 2. input GEMM: xz = xn @ W_in^T  (M=2048, N=4096, K=1024), bf16 out
  //    BMT=64 -> 1024 blocks (4 blocks/CU) for latency hiding
  gemm_mfma<1, 64><<<dim3(32, 32), 256, 0, stream>>>(
      xn_b, D_, Win_b, D_, nullptr, xz_b, 4096, 4096, D_, nullptr);
  // 3. dbl = conv_silu(xz) @ W_xproj^T, conv fused into A-staging; split-K x16
  //    atomicAdd into pre-zeroed dblb; xc_b written as staging side effect
  gemm_mfma<6, 128><<<dim3(1, 16, 16), 256, 0, stream>>>(
      xz_b, 4096, Wxp_b, D_INNER, dblb, xc_b, 96, 96, D_INNER, b_conv, W_conv);
  // 4. delta = softplus(dt_low @ W_dt^T + b_dt) -> bf16; A reg-staged from fp32 dblb
  gemm_mfma<5, 128><<<dim3(16, 16), 256, 0, stream>>>(
      nullptr, 96, Wdt_b, DT_RANK, nullptr, delta_b, D_INNER, D_INNER, DT_RANK, b_dt, dblb);
  // 5. chunked scan (NC=64, 3 kernels — proven correct)
  scan1_kernel<<<dim3(D_INNER / 256, B_, NC), 256, 0, stream>>>(delta_b, xc_b, dblb, A_log, P, Q);
  scan2_kernel<<<(B_ * N_STATE * D_INNER) / 256, 256, 0, stream>>>(P, Q);
  scan3_kernel<<<dim3(D_INNER / 256, B_, NC), 256, 0, stream>>>(delta_b, xc_b, dblb, A_log, Q,
                                                                xz_b, D_skip, y_b);
  // 6. out += y @ W_out^T  (split-K x2, atomicAdd; out pre-filled with residual x)
  gemm_mfma<7, 64><<<dim3(8, 32, 2), 256, 0, stream>>>(
      y_b, D_INNER, Wout_b, D_INNER, out, nullptr, D_, D_, D_INNER, nullptr);
}